// Round 6
// baseline (813.910 us; speedup 1.0000x reference)
//
#include <hip/hip_runtime.h>
#include <hip/hip_bf16.h>
#include <hip/hip_cooperative_groups.h>

namespace cg = cooperative_groups;

// CHNN=1024, K=L=2048. Inputs fp32, output fp32. bf16 MFMA (16x16x32), fp32
// acc, TN layout. Round 18: persistent COOPERATIVE mega-kernel. r13's wave
// body (barrier-free single-wave 64x64 tiles, XOR slot-swizzle, depth-3
// global_load_lds prefetch, vmcnt(16)) is unchanged; layers L2..L7 now run
// in ONE dispatch (1024 blocks x 64 thr, 4 blocks/CU, 24KB LDS) with 5
// grid.sync()s replacing 5 launch boundaries. Per-CU work per phase is
// identical to r13 (6 tiles/CU); the delta is launch gaps/tails, plus one
// big dispatch whose rocprof counters are finally visible over the fills.
// prep stays a separate normal launch (dataflow: r11/r13 arena).

typedef __bf16 bf16x4 __attribute__((ext_vector_type(4)));
typedef __bf16 bf16x8 __attribute__((ext_vector_type(8)));
typedef float  f32x4  __attribute__((ext_vector_type(4)));

typedef const void __attribute__((address_space(1)))* gptr_t;
typedef void       __attribute__((address_space(3)))* lptr_t;

__device__ __forceinline__ void load16_lds(const __bf16* g, __bf16* l)
{
    __builtin_amdgcn_global_load_lds((gptr_t)g, (lptr_t)l, 16, 0, 0);
}

// s_waitcnt imm (gfx9 encoding): vmcnt[3:0]|[15:14], expcnt[6:4], lgkmcnt[11:8]
#define WAITCNT_VM16 0x4F70  // vmcnt(16), no exp/lgkm wait
#define WAITCNT_VM8  0x0F78  // vmcnt(8)
#define WAITCNT_VM0  0x0F70  // vmcnt(0)

template<typename OT, int BIAS_, bool RELU_, int STORE_>
struct GC {
    using OUT_T = OT;
    static constexpr int BIAS = BIAS_, STORE = STORE_;
    static constexpr bool RELU = RELU_;
};

// Single-wave 64x64 TN GEMM body. C(M,N) = A(M,K)*B(N,K)^T (+bias, relu).
// sA/sB: 3 x 4KB LDS buffers each. BIAS: 0 none,1 row,2 col.
// STORE: 0 C[m][n] scalar, 1 CT[n][m] (16B vec over m).
template<class CF>
__device__ __forceinline__ void gemm_body(
    int bid, __bf16* sA, __bf16* sB,
    const __bf16* A, const __bf16* B,
    const float* bias,
    typename CF::OUT_T* C, typename CF::OUT_T* CT,
    int M, int N, int K, int ntx)
{
    const int lane = threadIdx.x & 63;
    const int m0 = (bid / ntx) * 64, n0 = (bid % ntx) * 64;
    const __bf16* gA = A + (size_t)m0 * K;
    const __bf16* gB = B + (size_t)n0 * K;

    f32x4 acc[4][4];
    #pragma unroll
    for (int i = 0; i < 4; ++i)
        #pragma unroll
        for (int j = 0; j < 4; ++j)
            acc[i][j] = (f32x4){0.f, 0.f, 0.f, 0.f};

    // stage one 64x32 bf16 tile pair (4KB+4KB). LDS chunk c=i*64+lane holds
    // row r=c>>2, slot (c&3); its CONTENT is global slot (c&3)^f(r) where
    // f(r)=((c>>2)^(c>>4))&3 — bank swizzle pre-applied on the global source
    // address (LDS dest stays linear: base + lane*16).
    auto stage = [&](int k0, int buf) {
        #pragma unroll
        for (int i = 0; i < 4; ++i) {
            const int c = i * 64 + lane;
            const int s = (c ^ (c >> 2) ^ (c >> 4)) & 3;
            load16_lds(gA + (size_t)(c >> 2) * K + k0 + s * 8,
                       &sA[buf * 2048 + i * 512]);
        }
        #pragma unroll
        for (int i = 0; i < 4; ++i) {
            const int c = i * 64 + lane;
            const int s = (c ^ (c >> 2) ^ (c >> 4)) & 3;
            load16_lds(gB + (size_t)(c >> 2) * K + k0 + s * 8,
                       &sB[buf * 2048 + i * 512]);
        }
    };

    // fragment read slot, same XOR: row = i*16+(lane&15) so
    // slot' = (lane>>4) ^ ((lane&3)^((lane>>2)&3)).
    const int fsw = ((lane >> 4) ^ lane ^ (lane >> 2)) & 3;

    auto compute = [&](int buf) {
        bf16x8 af[4], bfr[4];
        #pragma unroll
        for (int i = 0; i < 4; ++i) {
            const int off = buf * 2048 + (i * 16 + (lane & 15)) * 32 + fsw * 8;
            af[i]  = *(const bf16x8*)&sA[off];
            bfr[i] = *(const bf16x8*)&sB[off];
        }
        #pragma unroll
        for (int i = 0; i < 4; ++i)
            #pragma unroll
            for (int j = 0; j < 4; ++j)
                acc[i][j] = __builtin_amdgcn_mfma_f32_16x16x32_bf16(af[i], bfr[j], acc[i][j], 0, 0, 0);
    };

    stage(0, 0);
    stage(32, 1);
    stage(64, 2);
    int cur = 0;
    for (int k0 = 0; k0 < K - 96; k0 += 32) {
        __builtin_amdgcn_s_waitcnt(WAITCNT_VM16);   // cur's 8 loads retired
        compute(cur);
        stage(k0 + 96, cur);                        // refill after frags consumed
        cur = (cur == 2) ? 0 : cur + 1;
    }
    // peeled last 3 iterations: drain the pipeline
    __builtin_amdgcn_s_waitcnt(WAITCNT_VM16);
    compute(cur); cur = (cur == 2) ? 0 : cur + 1;
    __builtin_amdgcn_s_waitcnt(WAITCNT_VM8);
    compute(cur); cur = (cur == 2) ? 0 : cur + 1;
    __builtin_amdgcn_s_waitcnt(WAITCNT_VM0);
    compute(cur);

    // Epilogue. C/D layout: col=lane&15, row=(lane>>4)*4+reg (verified r6-r11).
    #pragma unroll
    for (int i = 0; i < 4; ++i) {
        const int rowb = m0 + i * 16 + (lane >> 4) * 4;
        #pragma unroll
        for (int j = 0; j < 4; ++j) {
            const int col = n0 + j * 16 + (lane & 15);
            f32x4 v = acc[i][j];
            #pragma unroll
            for (int r = 0; r < 4; ++r) {
                float f = v[r];
                if constexpr (CF::BIAS == 1) f += bias[rowb + r];
                if constexpr (CF::BIAS == 2) f += bias[col];
                if constexpr (CF::RELU) f = fmaxf(f, 0.f);
                v[r] = f;
            }
            if constexpr (CF::STORE == 0) {
                #pragma unroll
                for (int r = 0; r < 4; ++r)
                    C[(size_t)(rowb + r) * N + col] = (typename CF::OUT_T)v[r];
            } else {
                if constexpr (sizeof(typename CF::OUT_T) == 4) {
                    *(f32x4*)&CT[(size_t)col * M + rowb] = v;
                } else {
                    bf16x4 w = { (__bf16)v[0], (__bf16)v[1], (__bf16)v[2], (__bf16)v[3] };
                    *(bf16x4*)&CT[(size_t)col * M + rowb] = w;
                }
            }
        }
    }
}

// Single-wave row softmax over 2048 bf16 (32 elems/lane, shuffle reduce).
__device__ __forceinline__ void softmax_row_w(__bf16* p)
{
    const int lane = threadIdx.x & 63;
    bf16x8 v[4];
    float f[32];
    #pragma unroll
    for (int r = 0; r < 4; ++r)
        v[r] = *(const bf16x8*)&p[(r * 64 + lane) * 8];
    float m = -1e30f;
    #pragma unroll
    for (int r = 0; r < 4; ++r)
        #pragma unroll
        for (int j = 0; j < 8; ++j) {
            f[r * 8 + j] = (float)v[r][j];
            m = fmaxf(m, f[r * 8 + j]);
        }
    #pragma unroll
    for (int s = 1; s < 64; s <<= 1) m = fmaxf(m, __shfl_xor(m, s, 64));
    float sum = 0.f;
    #pragma unroll
    for (int i = 0; i < 32; ++i) { f[i] = expf(f[i] - m); sum += f[i]; }
    #pragma unroll
    for (int s = 1; s < 64; s <<= 1) sum += __shfl_xor(sum, s, 64);
    const float inv = 1.f / sum;
    #pragma unroll
    for (int r = 0; r < 4; ++r) {
        bf16x8 w;
        #pragma unroll
        for (int j = 0; j < 8; ++j) w[j] = (__bf16)(f[r * 8 + j] * inv);
        *(bf16x8*)&p[(r * 64 + lane) * 8] = w;
    }
}

using G3  = GC<__bf16, 2, false, 0>;   // ST = vcT*W_akb + b_ak[col]
using G5  = GC<__bf16, 1, true,  1>;   // vmrT = relu(W_cb*vmT + b_c[row])^T
using G6  = GC<__bf16, 0, false, 0>;   // vmm = W_madb*vmrT
using G11 = GC<__bf16, 1, false, 0>;   // xT = W_gcnT*vmrT + b_gcn[row]
using G7  = GC<__bf16, 2, false, 0>;   // vmaT = ST_sm*vmm + b_mad[col]
using G9  = GC<__bf16, 0, false, 0>;   // P = vmaT*vmaT^T
using G12 = GC<float,  0, false, 1>;   // out = (P_sm*xT)^T fp32

// Persistent cooperative kernel: L2..L7 with 5 grid syncs.
// Buffer reuse (time-separated): STP = ST then P; vcT -> vmaT;
// wakb -> vmm; vmTx = vmT then xT.
__global__ __launch_bounds__(64, 2)
void mega(__bf16* STP, __bf16* vcT, __bf16* wakb, __bf16* vmTx,
          __bf16* wcb, __bf16* wmadb, __bf16* vmrT, __bf16* wgcnT,
          const float* b_ak, const float* b_c, const float* b_mad,
          const float* b_gcn, float* out)
{
    __shared__ __bf16 sAB[12288];   // sA[3][2048] + sB[3][2048] = 24 KB
    __bf16* sA = sAB;
    __bf16* sB = sAB + 6144;
    cg::grid_group grid = cg::this_grid();
    const int nb = gridDim.x;

    // L2: [G3 1024 | G5 512]
    for (int it = blockIdx.x; it < 1536; it += nb) {
        if (it < 1024)
            gemm_body<G3>(it, sA, sB, vcT, wakb, b_ak, STP, (__bf16*)nullptr,
                          2048, 2048, 1024, 32);
        else
            gemm_body<G5>(it - 1024, sA, sB, wcb, vmTx, b_c,
                          (__bf16*)nullptr, vmrT, 1024, 2048, 1024, 32);
    }
    grid.sync();

    // L3: [G6 512 | G11 512 | softmax(ST) 2048]
    for (int it = blockIdx.x; it < 3072; it += nb) {
        if (it < 512)
            gemm_body<G6>(it, sA, sB, wmadb, vmrT, nullptr, wakb,
                          (__bf16*)nullptr, 1024, 2048, 1024, 32);
        else if (it < 1024)
            gemm_body<G11>(it - 512, sA, sB, wgcnT, vmrT, b_gcn, vmTx,
                           (__bf16*)nullptr, 1024, 2048, 1024, 32);
        else
            softmax_row_w(STP + (size_t)(it - 1024) * 2048);
    }
    grid.sync();

    // L4: G7 512 tiles (2048x1024 K2048): vmaT = ST_sm*vmm + b_mad
    for (int it = blockIdx.x; it < 512; it += nb)
        gemm_body<G7>(it, sA, sB, STP, wakb, b_mad, vcT, (__bf16*)nullptr,
                      2048, 1024, 2048, 16);
    grid.sync();

    // L5: G9 1024 tiles (2048x2048 K1024): P = vmaT*vmaT^T
    for (int it = blockIdx.x; it < 1024; it += nb)
        gemm_body<G9>(it, sA, sB, vcT, vcT, nullptr, STP, (__bf16*)nullptr,
                      2048, 2048, 1024, 32);
    grid.sync();

    // L6: softmax rows of P
    for (int it = blockIdx.x; it < 2048; it += nb)
        softmax_row_w(STP + (size_t)it * 2048);
    grid.sync();

    // L7: G12 512 tiles (2048x1024 K2048): out = (P_sm*xT)^T fp32
    for (int it = blockIdx.x; it < 512; it += nb)
        gemm_body<G12>(it, sA, sB, STP, vmTx, nullptr, (float*)nullptr, out,
                       2048, 1024, 2048, 16);
}

// ---------------- prep (unchanged, 256-thread) ----------------
__device__ __forceinline__ void tp_tile(const float* __restrict__ in,
                                        __bf16* __restrict__ outp,
                                        int R, int C, int bx, int by)
{
    __shared__ float t[32][33];
    const int tx = threadIdx.x & 31, ty = threadIdx.x >> 5;
    #pragma unroll
    for (int i = ty; i < 32; i += 8)
        t[i][tx] = in[(size_t)(by + i) * C + (bx + tx)];
    __syncthreads();
    #pragma unroll
    for (int i = ty; i < 32; i += 8)
        outp[(size_t)(bx + i) * R + (by + tx)] = (__bf16)t[tx][i];
}

__device__ __forceinline__ void cast_blk(const float* __restrict__ s,
                                         __bf16* __restrict__ d, int blk)
{
    const int i = blk * 1024 + threadIdx.x * 4;
    float4 v = *(const float4*)&s[i];
    bf16x4 w = { (__bf16)v.x, (__bf16)v.y, (__bf16)v.z, (__bf16)v.w };
    *(bf16x4*)&d[i] = w;
}

__global__ __launch_bounds__(256)
void prep(const float* __restrict__ vc, __bf16* __restrict__ vcT,
          const float* __restrict__ vm, __bf16* __restrict__ vmT,
          const float* __restrict__ W_ak, __bf16* __restrict__ W_akb,
          const float* __restrict__ W_c, __bf16* __restrict__ W_cb,
          const float* __restrict__ W_mad, __bf16* __restrict__ W_madb,
          const float* __restrict__ W_gcn, __bf16* __restrict__ W_gcnT)
{
    const int x = blockIdx.x;
    if (blockIdx.z == 0) {
        const float* in = (x < 2048) ? vc : vm;
        __bf16* o       = (x < 2048) ? vcT : vmT;
        const int e = x & 2047;
        tp_tile(in, o, 1024, 2048, (e & 63) * 32, (e >> 6) * 32);
    } else if (blockIdx.z == 1) {
        if (x < 2048)      cast_blk(W_ak, W_akb, x);
        else if (x < 3072) cast_blk(W_c, W_cb, x - 2048);
        else               cast_blk(W_mad, W_madb, x - 3072);
    } else {
        if (x >= 1024) return;
        tp_tile(W_gcn, W_gcnT, 1024, 1024, (x & 31) * 32, (x >> 5) * 32);
    }
}

extern "C" void kernel_launch(void* const* d_in, const int* in_sizes, int n_in,
                              void* d_out, int out_size, void* d_ws, size_t ws_size,
                              hipStream_t stream)
{
    const float* vc    = (const float*)d_in[0];
    const float* vm    = (const float*)d_in[1];
    const float* W_ak  = (const float*)d_in[2];
    const float* b_ak  = (const float*)d_in[3];
    const float* W_c   = (const float*)d_in[4];
    const float* b_c   = (const float*)d_in[5];
    const float* W_mad = (const float*)d_in[6];
    const float* b_mad = (const float*)d_in[7];
    const float* W_gcn = (const float*)d_in[8];
    const float* b_gcn = (const float*)d_in[9];
    float* out = (float*)d_out;

    // Arena, 32 MB (r13 layout):
    //  [0,8):   ST (wL2, smL3, rL4)  -> P (wL5, smL6, rL7)
    //  [8,12):  vcT (wL1, rL2)       -> vmaT (wL4, rL5)
    //  [12,16): W_akb (wL1, rL2)     -> vmm (wL3, rL4)
    //  [16,20): vmT (wL1, rL2)       -> xT (wL3, rL7)
    //  [20,22): W_cb (wL1, rL2)
    //  [22,24): W_madb (wL1, rL3)
    //  [24,28): vmrT (wL2, rL3)
    //  [28,30): W_gcnT (wL1, rL3)
    char* ws = (char*)d_ws;
    const size_t MB = 1u << 20;
    __bf16* STP    = (__bf16*)(ws);
    __bf16* vcT    = (__bf16*)(ws + 8 * MB);
    __bf16* W_akb  = (__bf16*)(ws + 12 * MB);
    __bf16* vmT    = (__bf16*)(ws + 16 * MB);
    __bf16* W_cb   = (__bf16*)(ws + 20 * MB);
    __bf16* W_madb = (__bf16*)(ws + 22 * MB);
    __bf16* vmrT   = (__bf16*)(ws + 24 * MB);
    __bf16* W_gcnT = (__bf16*)(ws + 28 * MB);

    // L1. input casts/transposes (normal launch)
    prep<<<dim3(4096, 1, 3), 256, 0, stream>>>(vc, vcT, vm, vmT, W_ak, W_akb,
                                               W_c, W_cb, W_mad, W_madb,
                                               W_gcn, W_gcnT);

    // L2..L7 in one cooperative dispatch (1024 blocks x 64 thr, 4/CU).
    void* args[] = {
        (void*)&STP, (void*)&vcT, (void*)&W_akb, (void*)&vmT,
        (void*)&W_cb, (void*)&W_madb, (void*)&vmrT, (void*)&W_gcnT,
        (void*)&b_ak, (void*)&b_c, (void*)&b_mad, (void*)&b_gcn,
        (void*)&out
    };
    hipLaunchCooperativeKernel((void*)mega, dim3(1024), dim3(64),
                               args, 0, stream);
}

// Round 7
// 198.103 us; speedup vs baseline: 4.1085x; 4.1085x over previous
//
#include <hip/hip_runtime.h>
#include <hip/hip_bf16.h>

// CHNN=1024, K=L=2048. Inputs fp32, output fp32. bf16 MFMA (16x16x32), fp32
// acc, TN layout. Round 19 = r13 (best measured, 198.5us) + SYMMETRIC L5:
// P = vmaT*vmaT^T is symmetric, so L5 computes only the 528 upper-triangular
// 64x64 tiles (of 1024) and mirror-stores off-diagonal tiles (mirror store is
// contiguous bf16x4 over rows). 48% less L5 compute+staged traffic.
// Everything else byte-identical to r13 (XOR slot-swizzle, depth-3 prefetch,
// barrier-free single-wave 64x64 blocks, 7 launches, vmm-associativity).
// r14-r18 lessons: atomics, K-split, 4-wave barrier tiles, coop persistence
// all regress; launch-per-phase + this wave body is the proven structure.

typedef __bf16 bf16x4 __attribute__((ext_vector_type(4)));
typedef __bf16 bf16x8 __attribute__((ext_vector_type(8)));
typedef float  f32x4  __attribute__((ext_vector_type(4)));

typedef const void __attribute__((address_space(1)))* gptr_t;
typedef void       __attribute__((address_space(3)))* lptr_t;

__device__ __forceinline__ void load16_lds(const __bf16* g, __bf16* l)
{
    __builtin_amdgcn_global_load_lds((gptr_t)g, (lptr_t)l, 16, 0, 0);
}

// s_waitcnt imm (gfx9 encoding): vmcnt[3:0]|[15:14], expcnt[6:4], lgkmcnt[11:8]
#define WAITCNT_VM16 0x4F70  // vmcnt(16), no exp/lgkm wait
#define WAITCNT_VM8  0x0F78  // vmcnt(8)
#define WAITCNT_VM0  0x0F70  // vmcnt(0)

template<typename OT, int BIAS_, bool RELU_, int STORE_>
struct GC {
    using OUT_T = OT;
    static constexpr int BIAS = BIAS_, STORE = STORE_;
    static constexpr bool RELU = RELU_;
};

// Single-wave 64x64 TN GEMM body. C(M,N) = A(M,K)*B(N,K)^T (+bias, relu).
// sA/sB: 3 x 4KB LDS buffers each. BIAS: 0 none,1 row,2 col.
// STORE: 0 C[m][n] scalar (+optional mirror C[n][m] for symmetric output),
//        1 CT[n][m] (16B vec over m).
template<class CF>
__device__ __forceinline__ void gemm_body(
    int bid, __bf16* sA, __bf16* sB,
    const __bf16* __restrict__ A, const __bf16* __restrict__ B,
    const float* __restrict__ bias,
    typename CF::OUT_T* __restrict__ C, typename CF::OUT_T* __restrict__ CT,
    int M, int N, int K, int ntx, bool mirror = false)
{
    const int lane = threadIdx.x & 63;
    const int m0 = (bid / ntx) * 64, n0 = (bid % ntx) * 64;
    const __bf16* gA = A + (size_t)m0 * K;
    const __bf16* gB = B + (size_t)n0 * K;

    f32x4 acc[4][4];
    #pragma unroll
    for (int i = 0; i < 4; ++i)
        #pragma unroll
        for (int j = 0; j < 4; ++j)
            acc[i][j] = (f32x4){0.f, 0.f, 0.f, 0.f};

    // stage one 64x32 bf16 tile pair (4KB+4KB). LDS chunk c=i*64+lane holds
    // row r=c>>2, slot (c&3); its CONTENT is global slot (c&3)^f(r) where
    // f(r)=((c>>2)^(c>>4))&3 — bank swizzle pre-applied on the global source
    // address (LDS dest stays linear: base + lane*16).
    auto stage = [&](int k0, int buf) {
        #pragma unroll
        for (int i = 0; i < 4; ++i) {
            const int c = i * 64 + lane;
            const int s = (c ^ (c >> 2) ^ (c >> 4)) & 3;
            load16_lds(gA + (size_t)(c >> 2) * K + k0 + s * 8,
                       &sA[buf * 2048 + i * 512]);
        }
        #pragma unroll
        for (int i = 0; i < 4; ++i) {
            const int c = i * 64 + lane;
            const int s = (c ^ (c >> 2) ^ (c >> 4)) & 3;
            load16_lds(gB + (size_t)(c >> 2) * K + k0 + s * 8,
                       &sB[buf * 2048 + i * 512]);
        }
    };

    // fragment read slot, same XOR: row = i*16+(lane&15) so
    // slot' = (lane>>4) ^ ((lane&3)^((lane>>2)&3)).
    const int fsw = ((lane >> 4) ^ lane ^ (lane >> 2)) & 3;

    auto compute = [&](int buf) {
        bf16x8 af[4], bfr[4];
        #pragma unroll
        for (int i = 0; i < 4; ++i) {
            const int off = buf * 2048 + (i * 16 + (lane & 15)) * 32 + fsw * 8;
            af[i]  = *(const bf16x8*)&sA[off];
            bfr[i] = *(const bf16x8*)&sB[off];
        }
        #pragma unroll
        for (int i = 0; i < 4; ++i)
            #pragma unroll
            for (int j = 0; j < 4; ++j)
                acc[i][j] = __builtin_amdgcn_mfma_f32_16x16x32_bf16(af[i], bfr[j], acc[i][j], 0, 0, 0);
    };

    stage(0, 0);
    stage(32, 1);
    stage(64, 2);
    int cur = 0;
    for (int k0 = 0; k0 < K - 96; k0 += 32) {
        __builtin_amdgcn_s_waitcnt(WAITCNT_VM16);   // cur's 8 loads retired
        compute(cur);
        stage(k0 + 96, cur);                        // refill after frags consumed
        cur = (cur == 2) ? 0 : cur + 1;
    }
    // peeled last 3 iterations: drain the pipeline
    __builtin_amdgcn_s_waitcnt(WAITCNT_VM16);
    compute(cur); cur = (cur == 2) ? 0 : cur + 1;
    __builtin_amdgcn_s_waitcnt(WAITCNT_VM8);
    compute(cur); cur = (cur == 2) ? 0 : cur + 1;
    __builtin_amdgcn_s_waitcnt(WAITCNT_VM0);
    compute(cur);

    // Epilogue. C/D layout: col=lane&15, row=(lane>>4)*4+reg (verified r6-r11).
    #pragma unroll
    for (int i = 0; i < 4; ++i) {
        const int rowb = m0 + i * 16 + (lane >> 4) * 4;
        #pragma unroll
        for (int j = 0; j < 4; ++j) {
            const int col = n0 + j * 16 + (lane & 15);
            f32x4 v = acc[i][j];
            #pragma unroll
            for (int r = 0; r < 4; ++r) {
                float f = v[r];
                if constexpr (CF::BIAS == 1) f += bias[rowb + r];
                if constexpr (CF::BIAS == 2) f += bias[col];
                if constexpr (CF::RELU) f = fmaxf(f, 0.f);
                v[r] = f;
            }
            if constexpr (CF::STORE == 0) {
                #pragma unroll
                for (int r = 0; r < 4; ++r)
                    C[(size_t)(rowb + r) * N + col] = (typename CF::OUT_T)v[r];
                if constexpr (sizeof(typename CF::OUT_T) == 2) {
                    if (mirror) {
                        // symmetric output: P[col][rowb..rowb+3] = v (contiguous)
                        bf16x4 w = { (__bf16)v[0], (__bf16)v[1],
                                     (__bf16)v[2], (__bf16)v[3] };
                        *(bf16x4*)&C[(size_t)col * N + rowb] = w;
                    }
                }
            } else {
                if constexpr (sizeof(typename CF::OUT_T) == 4) {
                    *(f32x4*)&CT[(size_t)col * M + rowb] = v;
                } else {
                    bf16x4 w = { (__bf16)v[0], (__bf16)v[1], (__bf16)v[2], (__bf16)v[3] };
                    *(bf16x4*)&CT[(size_t)col * M + rowb] = w;
                }
            }
        }
    }
}

// Single-wave row softmax over 2048 bf16 (32 elems/lane, shuffle reduce).
__device__ __forceinline__ void softmax_row_w(__bf16* __restrict__ p)
{
    const int lane = threadIdx.x & 63;
    bf16x8 v[4];
    float f[32];
    #pragma unroll
    for (int r = 0; r < 4; ++r)
        v[r] = *(const bf16x8*)&p[(r * 64 + lane) * 8];
    float m = -1e30f;
    #pragma unroll
    for (int r = 0; r < 4; ++r)
        #pragma unroll
        for (int j = 0; j < 8; ++j) {
            f[r * 8 + j] = (float)v[r][j];
            m = fmaxf(m, f[r * 8 + j]);
        }
    #pragma unroll
    for (int s = 1; s < 64; s <<= 1) m = fmaxf(m, __shfl_xor(m, s, 64));
    float sum = 0.f;
    #pragma unroll
    for (int i = 0; i < 32; ++i) { f[i] = expf(f[i] - m); sum += f[i]; }
    #pragma unroll
    for (int s = 1; s < 64; s <<= 1) sum += __shfl_xor(sum, s, 64);
    const float inv = 1.f / sum;
    #pragma unroll
    for (int r = 0; r < 4; ++r) {
        bf16x8 w;
        #pragma unroll
        for (int j = 0; j < 8; ++j) w[j] = (__bf16)(f[r * 8 + j] * inv);
        *(bf16x8*)&p[(r * 64 + lane) * 8] = w;
    }
}

template<class CF>
__global__ __launch_bounds__(64, 2)
void gemm1w(const __bf16* __restrict__ A, const __bf16* __restrict__ B,
            const float* __restrict__ bias,
            typename CF::OUT_T* __restrict__ C, typename CF::OUT_T* __restrict__ CT,
            int M, int N, int K, int ntx)
{
    __shared__ __bf16 sAB[12288];   // sA[3][2048] + sB[3][2048] = 24 KB
    gemm_body<CF>(blockIdx.x, sAB, sAB + 4096 + 2048, A, B, bias, C, CT, M, N, K, ntx);
}

// Triangular symmetric GEMM: C = A*A^T (square, ntx x ntx tile grid), only
// upper-triangular tiles (ti<=tj), mirror-store off-diagonal tiles.
template<class CF>
__global__ __launch_bounds__(64, 2)
void gemm1wsym(const __bf16* __restrict__ A,
               typename CF::OUT_T* __restrict__ C,
               int M, int K, int ntx)
{
    __shared__ __bf16 sAB[12288];
    int rem = blockIdx.x, ti = 0, rowlen = ntx;
    while (rem >= rowlen) { rem -= rowlen; ++ti; --rowlen; }
    const int tj = ti + rem;
    gemm_body<CF>(ti * ntx + tj, sAB, sAB + 6144, A, A, nullptr, C,
                  (typename CF::OUT_T*)nullptr, M, M, K, ntx, ti != tj);
}

// Two GEMMs fused.
template<class C1, class C2>
__global__ __launch_bounds__(64, 2)
void gemm2w(int nblk1,
            const __bf16* __restrict__ A1, const __bf16* __restrict__ B1,
            const float* __restrict__ b1,
            typename C1::OUT_T* __restrict__ C1p, typename C1::OUT_T* __restrict__ CT1,
            int M1, int N1, int K1, int ntx1,
            const __bf16* __restrict__ A2, const __bf16* __restrict__ B2,
            const float* __restrict__ b2,
            typename C2::OUT_T* __restrict__ C2p, typename C2::OUT_T* __restrict__ CT2,
            int M2, int N2, int K2, int ntx2)
{
    __shared__ __bf16 sAB[12288];
    const int b = blockIdx.x;
    if (b < nblk1)
        gemm_body<C1>(b, sAB, sAB + 6144, A1, B1, b1, C1p, CT1, M1, N1, K1, ntx1);
    else
        gemm_body<C2>(b - nblk1, sAB, sAB + 6144, A2, B2, b2, C2p, CT2, M2, N2, K2, ntx2);
}

// Two GEMMs + row-softmax batch fused.
template<class C1, class C2>
__global__ __launch_bounds__(64, 2)
void gemm2smw(int nblk1, int nblk2,
              const __bf16* __restrict__ A1, const __bf16* __restrict__ B1,
              const float* __restrict__ b1, typename C1::OUT_T* __restrict__ C1p,
              int M1, int N1, int K1, int ntx1,
              const __bf16* __restrict__ A2, const __bf16* __restrict__ B2,
              const float* __restrict__ b2, typename C2::OUT_T* __restrict__ C2p,
              int M2, int N2, int K2, int ntx2,
              __bf16* __restrict__ SM)
{
    __shared__ __bf16 sAB[12288];
    const int b = blockIdx.x;
    if (b < nblk1)
        gemm_body<C1>(b, sAB, sAB + 6144, A1, B1, b1, C1p,
                      (typename C1::OUT_T*)nullptr, M1, N1, K1, ntx1);
    else if (b < nblk1 + nblk2)
        gemm_body<C2>(b - nblk1, sAB, sAB + 6144, A2, B2, b2, C2p,
                      (typename C2::OUT_T*)nullptr, M2, N2, K2, ntx2);
    else
        softmax_row_w(SM + (size_t)(b - nblk1 - nblk2) * 2048);
}

__global__ __launch_bounds__(64)
void row_softmax_w(__bf16* __restrict__ A)
{
    softmax_row_w(A + (size_t)blockIdx.x * 2048);
}

// ---------------- prep (unchanged, 256-thread) ----------------
__device__ __forceinline__ void tp_tile(const float* __restrict__ in,
                                        __bf16* __restrict__ outp,
                                        int R, int C, int bx, int by)
{
    __shared__ float t[32][33];
    const int tx = threadIdx.x & 31, ty = threadIdx.x >> 5;
    #pragma unroll
    for (int i = ty; i < 32; i += 8)
        t[i][tx] = in[(size_t)(by + i) * C + (bx + tx)];
    __syncthreads();
    #pragma unroll
    for (int i = ty; i < 32; i += 8)
        outp[(size_t)(bx + i) * R + (by + tx)] = (__bf16)t[tx][i];
}

__device__ __forceinline__ void cast_blk(const float* __restrict__ s,
                                         __bf16* __restrict__ d, int blk)
{
    const int i = blk * 1024 + threadIdx.x * 4;
    float4 v = *(const float4*)&s[i];
    bf16x4 w = { (__bf16)v.x, (__bf16)v.y, (__bf16)v.z, (__bf16)v.w };
    *(bf16x4*)&d[i] = w;
}

__global__ __launch_bounds__(256)
void prep(const float* __restrict__ vc, __bf16* __restrict__ vcT,
          const float* __restrict__ vm, __bf16* __restrict__ vmT,
          const float* __restrict__ W_ak, __bf16* __restrict__ W_akb,
          const float* __restrict__ W_c, __bf16* __restrict__ W_cb,
          const float* __restrict__ W_mad, __bf16* __restrict__ W_madb,
          const float* __restrict__ W_gcn, __bf16* __restrict__ W_gcnT)
{
    const int x = blockIdx.x;
    if (blockIdx.z == 0) {
        const float* in = (x < 2048) ? vc : vm;
        __bf16* o       = (x < 2048) ? vcT : vmT;
        const int e = x & 2047;
        tp_tile(in, o, 1024, 2048, (e & 63) * 32, (e >> 6) * 32);
    } else if (blockIdx.z == 1) {
        if (x < 2048)      cast_blk(W_ak, W_akb, x);
        else if (x < 3072) cast_blk(W_c, W_cb, x - 2048);
        else               cast_blk(W_mad, W_madb, x - 3072);
    } else {
        if (x >= 1024) return;
        tp_tile(W_gcn, W_gcnT, 1024, 1024, (x & 31) * 32, (x >> 5) * 32);
    }
}

extern "C" void kernel_launch(void* const* d_in, const int* in_sizes, int n_in,
                              void* d_out, int out_size, void* d_ws, size_t ws_size,
                              hipStream_t stream)
{
    const float* vc    = (const float*)d_in[0];
    const float* vm    = (const float*)d_in[1];
    const float* W_ak  = (const float*)d_in[2];
    const float* b_ak  = (const float*)d_in[3];
    const float* W_c   = (const float*)d_in[4];
    const float* b_c   = (const float*)d_in[5];
    const float* W_mad = (const float*)d_in[6];
    const float* b_mad = (const float*)d_in[7];
    const float* W_gcn = (const float*)d_in[8];
    const float* b_gcn = (const float*)d_in[9];
    float* out = (float*)d_out;

    // Arena, 32 MB (r13 layout):
    //  [0,8):   ST (wL2, smL3, rL4)  -> P (wL5, smL6, rL7)
    //  [8,12):  vcT (wL1, rL2)       -> vmaT (wL4, rL5)
    //  [12,16): W_akb (wL1, rL2)     -> vmm (wL3, rL4)
    //  [16,20): vmT (wL1, rL2)       -> xT (wL3, rL7)
    //  [20,22): W_cb (wL1, rL2)
    //  [22,24): W_madb (wL1, rL3)
    //  [24,28): vmrT (wL2, rL3)
    //  [28,30): W_gcnT (wL1, rL3)
    char* ws = (char*)d_ws;
    const size_t MB = 1u << 20;
    __bf16* ST     = (__bf16*)(ws);
    __bf16* P      = (__bf16*)(ws);
    __bf16* vcT    = (__bf16*)(ws + 8 * MB);
    __bf16* vmaT   = (__bf16*)(ws + 8 * MB);
    __bf16* W_akb  = (__bf16*)(ws + 12 * MB);
    __bf16* vmm    = (__bf16*)(ws + 12 * MB);
    __bf16* vmT    = (__bf16*)(ws + 16 * MB);
    __bf16* xT     = (__bf16*)(ws + 16 * MB);
    __bf16* W_cb   = (__bf16*)(ws + 20 * MB);
    __bf16* W_madb = (__bf16*)(ws + 22 * MB);
    __bf16* vmrT   = (__bf16*)(ws + 24 * MB);
    __bf16* W_gcnT = (__bf16*)(ws + 28 * MB);

    using G3  = GC<__bf16, 2, false, 0>;   // ST = vcT*W_akb + b_ak[col]
    using G5  = GC<__bf16, 1, true,  1>;   // vmrT = relu(W_cb*vmT + b_c[row])^T
    using G6  = GC<__bf16, 0, false, 0>;   // vmm = W_madb*vmrT
    using G11 = GC<__bf16, 1, false, 0>;   // xT = W_gcnT*vmrT + b_gcn[row]
    using G7  = GC<__bf16, 2, false, 0>;   // vmaT = ST_sm*vmm + b_mad[col]
    using G9  = GC<__bf16, 0, false, 0>;   // P = vmaT*vmaT^T (symmetric)
    using G12 = GC<float,  0, false, 1>;   // out = (P_sm*xT)^T fp32

    // L1. input casts/transposes
    prep<<<dim3(4096, 1, 3), 256, 0, stream>>>(vc, vcT, vm, vmT, W_ak, W_akb,
                                               W_c, W_cb, W_mad, W_madb,
                                               W_gcn, W_gcnT);
    // L2. [G3 1024 | G5 512] = 1536 single-wave blocks
    gemm2w<G3, G5><<<1536, 64, 0, stream>>>(1024,
        vcT, W_akb, b_ak, ST, (__bf16*)nullptr, 2048, 2048, 1024, 32,
        W_cb, vmT, b_c, (__bf16*)nullptr, vmrT, 1024, 2048, 1024, 32);
    // L3. [G6 512 | G11 512 | smST 2048] = 3072 blocks
    gemm2smw<G6, G11><<<3072, 64, 0, stream>>>(512, 512,
        W_madb, vmrT, nullptr, vmm, 1024, 2048, 1024, 32,
        W_gcnT, vmrT, b_gcn, xT, 1024, 2048, 1024, 32,
        ST);
    // L4. G7: vmaT = ST_sm*vmm + b_mad (2048x1024 K2048), 512 blocks
    gemm1w<G7><<<512, 64, 0, stream>>>(ST, vmm, b_mad, vmaT, (__bf16*)nullptr,
                                       2048, 1024, 2048, 16);
    // L5. G9: P = vmaT*vmaT^T symmetric (2048x2048 K1024), 528 tri blocks
    gemm1wsym<G9><<<528, 64, 0, stream>>>(vmaT, P, 2048, 1024, 32);
    // L6. softmax rows of P
    row_softmax_w<<<2048, 64, 0, stream>>>(P);
    // L7. G12: out = (P_sm*xT)^T direct fp32 (2048x1024 K2048), 512 blocks
    gemm1w<G12><<<512, 64, 0, stream>>>(P, xT, nullptr, (float*)nullptr, out,
                                        2048, 1024, 2048, 16);
}